// Round 4
// baseline (962.992 us; speedup 1.0000x reference)
//
#include <hip/hip_runtime.h>

// Problem constants
static constexpr int N_   = 100000;
static constexpr int E_   = 1600000;
static constexpr int FIN_ = 128;
static constexpr int DIM_ = 32;
static constexpr int NC_  = 40;
static constexpr int NB_BKT = (N_ + 127) / 128;   // 782 buckets of 128 dst nodes
static constexpr int NCHUNK = 256;                // edge chunks (scatter blocks)
static constexpr int EPC    = E_ / NCHUNK;        // 6250 edges per chunk (exact)

// ---------------------------------------------------------------------------
// Edge dtype detection: reference says int64, but JAX x64-off gives int32.
// ---------------------------------------------------------------------------
__global__ void detect_kernel(const void* __restrict__ edge, int* __restrict__ flag) {
    if (blockIdx.x == 0 && threadIdx.x == 0) {
        const long long* p = (const long long*)edge;
        int ok = 1;
        for (int i = 0; i < 64; ++i) {
            long long v = p[i];
            if (v < 0 || v >= (long long)N_) { ok = 0; break; }
        }
        *flag = ok;   // 1 => int64 layout
    }
}

__device__ __forceinline__ int edge_at(const void* e, int is64, long long i) {
    return is64 ? (int)((const long long*)e)[i] : ((const int*)e)[i];
}

// ---------------------------------------------------------------------------
// Build 1: per-chunk bucket histogram in LDS -> ghist[b][k] (no global atomics)
// ---------------------------------------------------------------------------
__global__ __launch_bounds__(256) void chist_kernel(const void* __restrict__ edge,
                                                    const int* __restrict__ flag,
                                                    int* __restrict__ ghist) {
    __shared__ int lh[NB_BKT];
    for (int i = threadIdx.x; i < NB_BKT; i += 256) lh[i] = 0;
    __syncthreads();
    int f = *flag;
    int b = blockIdx.x;
    int end = b * EPC + EPC;
    for (int e = b * EPC + threadIdx.x; e < end; e += 256) {
        int d = edge_at(edge, f, (long long)E_ + e);
        atomicAdd(&lh[d >> 7], 1);           // LDS int atomic
    }
    __syncthreads();
    for (int i = threadIdx.x; i < NB_BKT; i += 256) ghist[b * NB_BKT + i] = lh[i];
}

// ---------------------------------------------------------------------------
// Build 2: per-bucket column scan of ghist -> gcurT[k][b] (excl) + bcnt[k]
// ---------------------------------------------------------------------------
__global__ __launch_bounds__(NCHUNK) void colscan_kernel(const int* __restrict__ ghist,
                                                         int* __restrict__ gcurT,
                                                         int* __restrict__ bcnt) {
    __shared__ int a[NCHUNK];
    int k = blockIdx.x, tid = threadIdx.x;
    int v = ghist[tid * NB_BKT + k];
    a[tid] = v;
    __syncthreads();
    for (int off = 1; off < NCHUNK; off <<= 1) {
        int t = a[tid] + ((tid >= off) ? a[tid - off] : 0);
        __syncthreads();
        a[tid] = t;
        __syncthreads();
    }
    gcurT[k * NCHUNK + tid] = a[tid] - v;    // exclusive within column
    if (tid == NCHUNK - 1) bcnt[k] = a[tid]; // column total
}

// ---------------------------------------------------------------------------
// Build 3: single-block exclusive scan of bucket totals -> bbase
// ---------------------------------------------------------------------------
__global__ __launch_bounds__(1024) void bscan_kernel(const int* __restrict__ bcnt,
                                                     int* __restrict__ bbase) {
    __shared__ int a[1024];
    int tid = threadIdx.x;
    int v = (tid < NB_BKT) ? bcnt[tid] : 0;
    a[tid] = v;
    __syncthreads();
    for (int off = 1; off < 1024; off <<= 1) {
        int t = a[tid] + ((tid >= off) ? a[tid - off] : 0);
        __syncthreads();
        a[tid] = t;
        __syncthreads();
    }
    if (tid < NB_BKT) bbase[tid] = a[tid] - v;
}

// ---------------------------------------------------------------------------
// Build 4: deterministic scatter. Each chunk-block owns exact sub-ranges of
// every bucket region; cursors live in LDS (int atomics, ~8 edges/bucket).
// ---------------------------------------------------------------------------
__global__ __launch_bounds__(256) void dscatter_kernel(const void* __restrict__ edge,
                                                       const int* __restrict__ flag,
                                                       const int* __restrict__ bbase,
                                                       const int* __restrict__ gcurT,
                                                       int* __restrict__ packed) {
    __shared__ int cur[NB_BKT];
    int b = blockIdx.x, tid = threadIdx.x;
    for (int k = tid; k < NB_BKT; k += 256) cur[k] = bbase[k] + gcurT[k * NCHUNK + b];
    __syncthreads();
    int f = *flag;
    int end = b * EPC + EPC;
    for (int e = b * EPC + tid; e < end; e += 256) {
        int s = edge_at(edge, f, e);
        int d = edge_at(edge, f, (long long)E_ + e);
        int pos = atomicAdd(&cur[d >> 7], 1);     // LDS int atomic
        packed[pos] = s | ((d & 127) << 17);      // N < 2^17
    }
}

// ---------------------------------------------------------------------------
// y = x @ w1a   (100000x128 @ 128x32). 32 nodes per block, 256 threads.
// ---------------------------------------------------------------------------
__global__ __launch_bounds__(256) void proj1_kernel(const float* __restrict__ x,
                                                    const float* __restrict__ w,
                                                    float* __restrict__ y) {
    __shared__ float wsm[FIN_ * DIM_];   // w[k][d]
    __shared__ float xs[32][FIN_];       // 32 node rows
    int tid = threadIdx.x;

    const float4* w4 = (const float4*)w;
    float4* ws4 = (float4*)wsm;
    for (int i = tid; i < FIN_ * DIM_ / 4; i += 256) ws4[i] = w4[i];

    int nodeBase = blockIdx.x * 32;
    const float4* x4 = (const float4*)(x + (size_t)nodeBase * FIN_);
    float4* xs4 = (float4*)&xs[0][0];
    for (int i = tid; i < 32 * FIN_ / 4; i += 256) xs4[i] = x4[i];
    __syncthreads();

    int d = tid & 31, ns = tid >> 5;     // ns in [0,8)
    for (int rep = 0; rep < 4; ++rep) {
        int node = ns + rep * 8;
        float acc = 0.f;
#pragma unroll 4
        for (int k = 0; k < FIN_; ++k) acc += xs[node][k] * wsm[k * DIM_ + d];
        y[(size_t)(nodeBase + node) * DIM_ + d] = acc;
    }
}

// ---------------------------------------------------------------------------
// Per-bucket aggregation: block = bucket of 128 dst nodes. LDS accumulator
// (row-padded to 33 floats to spread banks), ds_add_f32 sinks, coalesced out.
// ---------------------------------------------------------------------------
__global__ __launch_bounds__(256) void agg_bucket_kernel(const int* __restrict__ bbase,
                                                         const int* __restrict__ bcnt,
                                                         const int* __restrict__ packed,
                                                         const float* __restrict__ vec,
                                                         float* __restrict__ agg) {
    __shared__ float acc[128 * 33];
    int b = blockIdx.x, tid = threadIdx.x;
    for (int i = tid; i < 128 * 33; i += 256) acc[i] = 0.f;
    __syncthreads();

    int beg = bbase[b], cnt = bcnt[b];
    int lane = tid & 7;                       // float4 slot within 32-dim row
    for (int i = tid >> 3; i < cnt; i += 32) {
        int v  = packed[beg + i];
        int s  = v & 0x1FFFF;
        int dl = v >> 17;
        float4 r = ((const float4*)(vec + (size_t)s * DIM_))[lane];
        float* p = &acc[dl * 33 + lane * 4];
        unsafeAtomicAdd(p + 0, r.x);
        unsafeAtomicAdd(p + 1, r.y);
        unsafeAtomicAdd(p + 2, r.z);
        unsafeAtomicAdd(p + 3, r.w);
    }
    __syncthreads();

    int nodeBase = b * 128;
    for (int i = tid; i < 128 * DIM_; i += 256) {
        int dl = i >> 5, d = i & 31;
        int node = nodeBase + dl;
        if (node < N_) agg[(size_t)node * DIM_ + d] = acc[dl * 33 + d];
    }
}

// ---------------------------------------------------------------------------
// Node MLP 1: u=relu(agg+y+b1a); h=u@w1b+b1b; hb=bn1(relu(h)); z = hb@w2a.
// z written IN PLACE over y (read-before-write by same thread).
// ---------------------------------------------------------------------------
__global__ __launch_bounds__(256) void mlp1_kernel(float* yz,
                                                   const float* __restrict__ agg,
                                                   const float* __restrict__ b1a,
                                                   const float* __restrict__ w1b,
                                                   const float* __restrict__ b1b,
                                                   const float* __restrict__ g1,
                                                   const float* __restrict__ be1,
                                                   const float* __restrict__ m1,
                                                   const float* __restrict__ v1,
                                                   const float* __restrict__ w2a) {
    __shared__ float w1s[DIM_ * DIM_];
    __shared__ float w2s[DIM_ * DIM_];
    __shared__ float s[8][DIM_ + 1];
    int tid = threadIdx.x;
    for (int i = tid; i < DIM_ * DIM_; i += 256) { w1s[i] = w1b[i]; w2s[i] = w2a[i]; }

    int d = tid & 31, ns = tid >> 5;
    int node = blockIdx.x * 8 + ns;
    size_t base = (size_t)node * DIM_ + d;

    float sc1 = g1[d] * rsqrtf(v1[d] + 1e-5f);
    float sh1 = be1[d] - m1[d] * sc1;

    float u = fmaxf(agg[base] + yz[base] + b1a[d], 0.f);
    s[ns][d] = u;
    __syncthreads();

    float acc = b1b[d];
#pragma unroll
    for (int k = 0; k < DIM_; ++k) acc += s[ns][k] * w1s[k * DIM_ + d];
    float hb = fmaxf(acc, 0.f) * sc1 + sh1;   // relu then bn1
    __syncthreads();
    s[ns][d] = hb;
    __syncthreads();

    float acc2 = 0.f;
#pragma unroll
    for (int k = 0; k < DIM_; ++k) acc2 += s[ns][k] * w2s[k * DIM_ + d];
    yz[base] = acc2;
}

// ---------------------------------------------------------------------------
// Node MLP 2 + head: u=relu(agg2+z+b2a); h2=u@w2b+b2b; hb=bn2(h2);
// f=relu(hb@fc1w+fc1b); logits=f@fc2w+fc2b; out=log_softmax(logits).
// ---------------------------------------------------------------------------
__global__ __launch_bounds__(256) void mlp2_kernel(const float* __restrict__ z,
                                                   const float* __restrict__ agg,
                                                   const float* __restrict__ b2a,
                                                   const float* __restrict__ w2b,
                                                   const float* __restrict__ b2b,
                                                   const float* __restrict__ g2,
                                                   const float* __restrict__ be2,
                                                   const float* __restrict__ m2,
                                                   const float* __restrict__ v2,
                                                   const float* __restrict__ f1w,
                                                   const float* __restrict__ f1b,
                                                   const float* __restrict__ f2w,
                                                   const float* __restrict__ f2b,
                                                   float* __restrict__ out) {
    __shared__ float wA[DIM_ * DIM_];
    __shared__ float wB[DIM_ * DIM_];
    __shared__ float wC[DIM_ * NC_];
    __shared__ float s[8][DIM_ + 1];
    int tid = threadIdx.x;
    for (int i = tid; i < DIM_ * DIM_; i += 256) { wA[i] = w2b[i]; wB[i] = f1w[i]; }
    for (int i = tid; i < DIM_ * NC_; i += 256) wC[i] = f2w[i];

    int d = tid & 31, ns = tid >> 5;
    int node = blockIdx.x * 8 + ns;
    size_t base = (size_t)node * DIM_ + d;

    float sc2 = g2[d] * rsqrtf(v2[d] + 1e-5f);
    float sh2 = be2[d] - m2[d] * sc2;

    float u = fmaxf(agg[base] + z[base] + b2a[d], 0.f);
    s[ns][d] = u;
    __syncthreads();

    float acc = b2b[d];
#pragma unroll
    for (int k = 0; k < DIM_; ++k) acc += s[ns][k] * wA[k * DIM_ + d];
    float hb = acc * sc2 + sh2;               // bn2, NO relu between conv2 and bn2
    __syncthreads();
    s[ns][d] = hb;
    __syncthreads();

    float f = f1b[d];
#pragma unroll
    for (int k = 0; k < DIM_; ++k) f += s[ns][k] * wB[k * DIM_ + d];
    f = fmaxf(f, 0.f);
    __syncthreads();
    s[ns][d] = f;
    __syncthreads();

    int c2 = 32 + (d & 7);
    float l0 = f2b[d];
    float l1 = f2b[c2];
#pragma unroll
    for (int k = 0; k < DIM_; ++k) {
        float fv = s[ns][k];
        l0 += fv * wC[k * NC_ + d];
        l1 += fv * wC[k * NC_ + c2];
    }

    float mx = fmaxf(l0, l1);
#pragma unroll
    for (int off = 16; off; off >>= 1) mx = fmaxf(mx, __shfl_xor(mx, off));
    float se = __expf(l0 - mx) + ((d < 8) ? __expf(l1 - mx) : 0.f);
#pragma unroll
    for (int off = 16; off; off >>= 1) se += __shfl_xor(se, off);
    float lse = mx + __logf(se);

    out[(size_t)node * NC_ + d] = l0 - lse;
    if (d < 8) out[(size_t)node * NC_ + 32 + d] = l1 - lse;
}

// ---------------------------------------------------------------------------
extern "C" void kernel_launch(void* const* d_in, const int* in_sizes, int n_in,
                              void* d_out, int out_size, void* d_ws, size_t ws_size,
                              hipStream_t stream) {
    const float* x   = (const float*)d_in[0];
    const void*  edg = d_in[1];
    const float* w1a = (const float*)d_in[2];
    const float* b1a = (const float*)d_in[3];
    const float* w1b = (const float*)d_in[4];
    const float* b1b = (const float*)d_in[5];
    const float* w2a = (const float*)d_in[6];
    const float* b2a = (const float*)d_in[7];
    const float* w2b = (const float*)d_in[8];
    const float* b2b = (const float*)d_in[9];
    const float* g1  = (const float*)d_in[10];
    const float* be1 = (const float*)d_in[11];
    const float* m1  = (const float*)d_in[12];
    const float* v1  = (const float*)d_in[13];
    const float* g2  = (const float*)d_in[14];
    const float* be2 = (const float*)d_in[15];
    const float* m2  = (const float*)d_in[16];
    const float* v2  = (const float*)d_in[17];
    const float* f1w = (const float*)d_in[18];
    const float* f1b = (const float*)d_in[19];
    const float* f2w = (const float*)d_in[20];
    const float* f2b = (const float*)d_in[21];
    float* out = (float*)d_out;

    // Workspace layout (offsets in bytes, 128B-aligned)
    char* ws = (char*)d_ws;
    int*   flag   = (int*)ws;                      // 256 B
    int*   bcnt   = (int*)(ws + 256);              // 782 ints (pad to 3328)
    int*   bbase  = (int*)(ws + 3584);             // 782 ints (pad to 3328)
    int*   ghist  = (int*)(ws + 6912);             // 256*782 ints = 800768 B
    int*   gcurT  = (int*)(ws + 807680);           // 782*256 ints = 800768 B
    int*   packed = (int*)(ws + 1608448);          // E ints = 6.4 MB
    float* y      = (float*)(ws + 8008448);        // N*DIM floats (also z)
    float* agg    = (float*)(ws + 20808448);       // N*DIM floats

    detect_kernel<<<1, 64, 0, stream>>>(edg, flag);

    // ---- Build bucketed edge list (no global atomics anywhere) ----
    chist_kernel<<<NCHUNK, 256, 0, stream>>>(edg, flag, ghist);
    colscan_kernel<<<NB_BKT, NCHUNK, 0, stream>>>(ghist, gcurT, bcnt);
    bscan_kernel<<<1, 1024, 0, stream>>>(bcnt, bbase);
    dscatter_kernel<<<NCHUNK, 256, 0, stream>>>(edg, flag, bbase, gcurT, packed);

    // ---- Layer 1: project 128->32 BEFORE aggregation (linearity) ----
    proj1_kernel<<<N_ / 32, 256, 0, stream>>>(x, w1a, y);
    agg_bucket_kernel<<<NB_BKT, 256, 0, stream>>>(bbase, bcnt, packed, y, agg);
    mlp1_kernel<<<N_ / 8, 256, 0, stream>>>(y, agg, b1a, w1b, b1b, g1, be1, m1, v1, w2a);

    // ---- Layer 2: aggregate z = bn1(h) @ w2a (w2a folded pre-aggregation) ----
    agg_bucket_kernel<<<NB_BKT, 256, 0, stream>>>(bbase, bcnt, packed, y, agg);
    mlp2_kernel<<<N_ / 8, 256, 0, stream>>>(y, agg, b2a, w2b, b2b, g2, be2, m2, v2,
                                            f1w, f1b, f2w, f2b, out);
}

// Round 5
// 357.131 us; speedup vs baseline: 2.6965x; 2.6965x over previous
//
#include <hip/hip_runtime.h>
#include <hip/hip_bf16.h>

// Problem constants
static constexpr int N_   = 100000;
static constexpr int E_   = 1600000;
static constexpr int FIN_ = 128;
static constexpr int DIM_ = 32;
static constexpr int NC_  = 40;
static constexpr int NB_BKT = (N_ + 127) / 128;   // 782 buckets of 128 dst nodes
static constexpr int NCHUNK = 512;                // edge chunks
static constexpr int EPC    = E_ / NCHUNK;        // 3125 edges per chunk (exact)

// ---------------------------------------------------------------------------
// Edge dtype detection: reference says int64, but JAX x64-off gives int32.
// ---------------------------------------------------------------------------
__global__ void detect_kernel(const void* __restrict__ edge, int* __restrict__ flag) {
    if (blockIdx.x == 0 && threadIdx.x == 0) {
        const long long* p = (const long long*)edge;
        int ok = 1;
        for (int i = 0; i < 64; ++i) {
            long long v = p[i];
            if (v < 0 || v >= (long long)N_) { ok = 0; break; }
        }
        *flag = ok;   // 1 => int64 layout
    }
}

__device__ __forceinline__ int edge_at(const void* e, int is64, long long i) {
    return is64 ? (int)((const long long*)e)[i] : ((const int*)e)[i];
}

__device__ __forceinline__ float bflo(unsigned u) { return __uint_as_float(u << 16); }
__device__ __forceinline__ float bfhi(unsigned u) { return __uint_as_float(u & 0xffff0000u); }

// ---------------------------------------------------------------------------
// Build 1: per-chunk bucket histogram in LDS -> ghist[b][k]  (no global atomics)
// ---------------------------------------------------------------------------
__global__ __launch_bounds__(256) void chist_kernel(const void* __restrict__ edge,
                                                    const int* __restrict__ flag,
                                                    int* __restrict__ ghist) {
    __shared__ int lh[NB_BKT];
    for (int i = threadIdx.x; i < NB_BKT; i += 256) lh[i] = 0;
    __syncthreads();
    int f = *flag;
    int b = blockIdx.x;
    int end = b * EPC + EPC;
    for (int e = b * EPC + threadIdx.x; e < end; e += 256) {
        int d = edge_at(edge, f, (long long)E_ + e);
        atomicAdd(&lh[d >> 7], 1);           // LDS int atomic
    }
    __syncthreads();
    for (int i = threadIdx.x; i < NB_BKT; i += 256) ghist[b * NB_BKT + i] = lh[i];
}

// ---------------------------------------------------------------------------
// Build 2: per-bucket column scan of ghist -> gcurT[k][b] (excl) + bcnt[k]
// ---------------------------------------------------------------------------
__global__ __launch_bounds__(512) void colscan_kernel(const int* __restrict__ ghist,
                                                      int* __restrict__ gcurT,
                                                      int* __restrict__ bcnt) {
    __shared__ int a[NCHUNK];
    int k = blockIdx.x, tid = threadIdx.x;
    int v = ghist[tid * NB_BKT + k];
    a[tid] = v;
    __syncthreads();
    for (int off = 1; off < NCHUNK; off <<= 1) {
        int t = a[tid] + ((tid >= off) ? a[tid - off] : 0);
        __syncthreads();
        a[tid] = t;
        __syncthreads();
    }
    gcurT[k * NCHUNK + tid] = a[tid] - v;     // exclusive within column
    if (tid == NCHUNK - 1) bcnt[k] = a[tid];  // column total
}

// ---------------------------------------------------------------------------
// Build 3: single-block exclusive scan of bucket totals -> bbase, offs[N]=E
// ---------------------------------------------------------------------------
__global__ __launch_bounds__(1024) void bscan_kernel(const int* __restrict__ bcnt,
                                                     int* __restrict__ bbase,
                                                     int* __restrict__ offs) {
    __shared__ int a[1024];
    int tid = threadIdx.x;
    int v = (tid < NB_BKT) ? bcnt[tid] : 0;
    a[tid] = v;
    __syncthreads();
    for (int off = 1; off < 1024; off <<= 1) {
        int t = a[tid] + ((tid >= off) ? a[tid - off] : 0);
        __syncthreads();
        a[tid] = t;
        __syncthreads();
    }
    if (tid < NB_BKT) bbase[tid] = a[tid] - v;
    if (tid == NB_BKT - 1) offs[N_] = a[tid];   // == E_
}

// ---------------------------------------------------------------------------
// Build 4: deterministic scatter into bucket regions; cursors in LDS.
// ---------------------------------------------------------------------------
__global__ __launch_bounds__(256) void dscatter_kernel(const void* __restrict__ edge,
                                                       const int* __restrict__ flag,
                                                       const int* __restrict__ bbase,
                                                       const int* __restrict__ gcurT,
                                                       int* __restrict__ packed) {
    __shared__ int cur[NB_BKT];
    int b = blockIdx.x, tid = threadIdx.x;
    for (int k = tid; k < NB_BKT; k += 256) cur[k] = bbase[k] + gcurT[k * NCHUNK + b];
    __syncthreads();
    int f = *flag;
    int end = b * EPC + EPC;
    for (int e = b * EPC + tid; e < end; e += 256) {
        int s = edge_at(edge, f, e);
        int d = edge_at(edge, f, (long long)E_ + e);
        int pos = atomicAdd(&cur[d >> 7], 1);     // LDS int atomic
        packed[pos] = s | ((d & 127) << 17);      // N < 2^17
    }
}

// ---------------------------------------------------------------------------
// Build 5: per-bucket counting sort in LDS -> exact offs[] + csr[] (src ids).
// All global writes confined to this bucket's contiguous region.
// ---------------------------------------------------------------------------
__global__ __launch_bounds__(256) void bsort_kernel(const int* __restrict__ bcnt,
                                                    const int* __restrict__ bbase,
                                                    const int* __restrict__ packed,
                                                    int* __restrict__ offs,
                                                    int* __restrict__ csr) {
    __shared__ int c[128];
    __shared__ int cur[128];
    int tid = threadIdx.x;
    int b = blockIdx.x;
    int beg = bbase[b], cnt = bcnt[b];
    if (tid < 128) c[tid] = 0;
    __syncthreads();
    for (int i = tid; i < cnt; i += 256)
        atomicAdd(&c[packed[beg + i] >> 17], 1);
    __syncthreads();
    int myv = (tid < 128) ? c[tid] : 0;
    for (int off = 1; off < 128; off <<= 1) {
        int t = 0;
        if (tid < 128) t = c[tid] + ((tid >= off) ? c[tid - off] : 0);
        __syncthreads();
        if (tid < 128) c[tid] = t;
        __syncthreads();
    }
    if (tid < 128) {
        int ex = c[tid] - myv;
        cur[tid] = ex;
        int node = b * 128 + tid;
        if (node < N_) offs[node] = beg + ex;
    }
    __syncthreads();
    for (int i = tid; i < cnt; i += 256) {
        int v = packed[beg + i];
        int p = atomicAdd(&cur[v >> 17], 1);
        csr[beg + p] = v & 0x1FFFF;
    }
}

// ---------------------------------------------------------------------------
// yh = bf16(x @ w1a)   (100000x128 @ 128x32). 32 nodes per block.
// ---------------------------------------------------------------------------
__global__ __launch_bounds__(256) void proj1_kernel(const float* __restrict__ x,
                                                    const float* __restrict__ w,
                                                    __hip_bfloat16* __restrict__ yh) {
    __shared__ float wsm[FIN_ * DIM_];
    __shared__ float xs[32][FIN_];
    int tid = threadIdx.x;

    const float4* w4 = (const float4*)w;
    float4* ws4 = (float4*)wsm;
    for (int i = tid; i < FIN_ * DIM_ / 4; i += 256) ws4[i] = w4[i];

    int nodeBase = blockIdx.x * 32;
    const float4* x4 = (const float4*)(x + (size_t)nodeBase * FIN_);
    float4* xs4 = (float4*)&xs[0][0];
    for (int i = tid; i < 32 * FIN_ / 4; i += 256) xs4[i] = x4[i];
    __syncthreads();

    int d = tid & 31, ns = tid >> 5;
    for (int rep = 0; rep < 4; ++rep) {
        int node = ns + rep * 8;
        float acc = 0.f;
#pragma unroll 4
        for (int k = 0; k < FIN_; ++k) acc += xs[node][k] * wsm[k * DIM_ + d];
        yh[(size_t)(nodeBase + node) * DIM_ + d] = __float2bfloat16(acc);
    }
}

// ---------------------------------------------------------------------------
// Fused 1: CSR gather over bf16 y (8 lanes x 8B per node, 32 nodes/block)
// then u=relu(agg+y+b1a); hb=bn1(relu(u@w1b+b1b)); zh=bf16(hb@w2a).
// ---------------------------------------------------------------------------
__global__ __launch_bounds__(256) void aggmlp1_kernel(const int* __restrict__ offs,
                                                      const int* __restrict__ csr,
                                                      const __hip_bfloat16* __restrict__ yh,
                                                      const float* __restrict__ b1a,
                                                      const float* __restrict__ w1b,
                                                      const float* __restrict__ b1b,
                                                      const float* __restrict__ g1,
                                                      const float* __restrict__ be1,
                                                      const float* __restrict__ m1,
                                                      const float* __restrict__ v1,
                                                      const float* __restrict__ w2a,
                                                      __hip_bfloat16* __restrict__ zh) {
    __shared__ float A[32 * 33];
    __shared__ float B[32 * 33];
    __shared__ float w1s[DIM_ * DIM_];
    __shared__ float w2s[DIM_ * DIM_];
    int tid = threadIdx.x;
    for (int i = tid; i < DIM_ * DIM_; i += 256) { w1s[i] = w1b[i]; w2s[i] = w2a[i]; }

    // --- gather-aggregate phase ---
    int nl = tid >> 3, lane = tid & 7;       // 8 lanes x 8B = one 64B row
    int node = blockIdx.x * 32 + nl;
    int beg = offs[node], end = offs[node + 1];
    float a0 = 0.f, a1 = 0.f, a2 = 0.f, a3 = 0.f;
    const char* vb = (const char*)yh;
    int loff = lane << 3;
    int i = beg;
    for (; i + 1 < end; i += 2) {
        int s0 = csr[i], s1 = csr[i + 1];
        uint2 u0 = *(const uint2*)(vb + (((size_t)s0) << 6) + loff);
        uint2 u1 = *(const uint2*)(vb + (((size_t)s1) << 6) + loff);
        a0 += bflo(u0.x) + bflo(u1.x); a1 += bfhi(u0.x) + bfhi(u1.x);
        a2 += bflo(u0.y) + bflo(u1.y); a3 += bfhi(u0.y) + bfhi(u1.y);
    }
    if (i < end) {
        int s0 = csr[i];
        uint2 u0 = *(const uint2*)(vb + (((size_t)s0) << 6) + loff);
        a0 += bflo(u0.x); a1 += bfhi(u0.x); a2 += bflo(u0.y); a3 += bfhi(u0.y);
    }
    {
        float* p = &A[nl * 33 + lane * 4];
        p[0] = a0; p[1] = a1; p[2] = a2; p[3] = a3;
    }
    __syncthreads();

    int d = tid & 31, ng = tid >> 5;
    size_t gbase = (size_t)blockIdx.x * 32 * DIM_;

    // u = relu(agg + y + b1a)  (elementwise, in place over A)
#pragma unroll
    for (int r = 0; r < 4; ++r) {
        int n = r * 8 + ng;
        float yv = __bfloat162float(yh[gbase + n * DIM_ + d]);
        A[n * 33 + d] = fmaxf(A[n * 33 + d] + yv + b1a[d], 0.f);
    }
    __syncthreads();

    float sc1 = g1[d] * rsqrtf(v1[d] + 1e-5f);
    float sh1 = be1[d] - m1[d] * sc1;

    // hb = bn1(relu(u @ w1b + b1b))
#pragma unroll
    for (int r = 0; r < 4; ++r) {
        int n = r * 8 + ng;
        float acc = b1b[d];
#pragma unroll
        for (int k = 0; k < DIM_; ++k) acc += A[n * 33 + k] * w1s[k * DIM_ + d];
        B[n * 33 + d] = fmaxf(acc, 0.f) * sc1 + sh1;
    }
    __syncthreads();

    // z = hb @ w2a  -> bf16
#pragma unroll
    for (int r = 0; r < 4; ++r) {
        int n = r * 8 + ng;
        float acc = 0.f;
#pragma unroll
        for (int k = 0; k < DIM_; ++k) acc += B[n * 33 + k] * w2s[k * DIM_ + d];
        zh[gbase + n * DIM_ + d] = __float2bfloat16(acc);
    }
}

// ---------------------------------------------------------------------------
// Fused 2: CSR gather over bf16 z, then u=relu(agg+z+b2a); hb=bn2(u@w2b+b2b);
// f=relu(hb@fc1w+fc1b); logits=f@fc2w+fc2b; out=log_softmax(logits).
// ---------------------------------------------------------------------------
__global__ __launch_bounds__(256) void aggmlp2_kernel(const int* __restrict__ offs,
                                                      const int* __restrict__ csr,
                                                      const __hip_bfloat16* __restrict__ zh,
                                                      const float* __restrict__ b2a,
                                                      const float* __restrict__ w2b,
                                                      const float* __restrict__ b2b,
                                                      const float* __restrict__ g2,
                                                      const float* __restrict__ be2,
                                                      const float* __restrict__ m2,
                                                      const float* __restrict__ v2,
                                                      const float* __restrict__ f1w,
                                                      const float* __restrict__ f1b,
                                                      const float* __restrict__ f2w,
                                                      const float* __restrict__ f2b,
                                                      float* __restrict__ out) {
    __shared__ float A[32 * 33];
    __shared__ float B[32 * 33];
    __shared__ float wA[DIM_ * DIM_];
    __shared__ float wB[DIM_ * DIM_];
    __shared__ float wC[DIM_ * NC_];
    int tid = threadIdx.x;
    for (int i = tid; i < DIM_ * DIM_; i += 256) { wA[i] = w2b[i]; wB[i] = f1w[i]; }
    for (int i = tid; i < DIM_ * NC_; i += 256) wC[i] = f2w[i];

    // --- gather-aggregate phase ---
    int nl = tid >> 3, lane = tid & 7;
    int node = blockIdx.x * 32 + nl;
    int beg = offs[node], end = offs[node + 1];
    float a0 = 0.f, a1 = 0.f, a2 = 0.f, a3 = 0.f;
    const char* vb = (const char*)zh;
    int loff = lane << 3;
    int i = beg;
    for (; i + 1 < end; i += 2) {
        int s0 = csr[i], s1 = csr[i + 1];
        uint2 u0 = *(const uint2*)(vb + (((size_t)s0) << 6) + loff);
        uint2 u1 = *(const uint2*)(vb + (((size_t)s1) << 6) + loff);
        a0 += bflo(u0.x) + bflo(u1.x); a1 += bfhi(u0.x) + bfhi(u1.x);
        a2 += bflo(u0.y) + bflo(u1.y); a3 += bfhi(u0.y) + bfhi(u1.y);
    }
    if (i < end) {
        int s0 = csr[i];
        uint2 u0 = *(const uint2*)(vb + (((size_t)s0) << 6) + loff);
        a0 += bflo(u0.x); a1 += bfhi(u0.x); a2 += bflo(u0.y); a3 += bfhi(u0.y);
    }
    {
        float* p = &A[nl * 33 + lane * 4];
        p[0] = a0; p[1] = a1; p[2] = a2; p[3] = a3;
    }
    __syncthreads();

    int d = tid & 31, ng = tid >> 5;
    size_t gbase = (size_t)blockIdx.x * 32 * DIM_;

    // u2 = relu(agg + z + b2a)
#pragma unroll
    for (int r = 0; r < 4; ++r) {
        int n = r * 8 + ng;
        float zv = __bfloat162float(zh[gbase + n * DIM_ + d]);
        A[n * 33 + d] = fmaxf(A[n * 33 + d] + zv + b2a[d], 0.f);
    }
    __syncthreads();

    float sc2 = g2[d] * rsqrtf(v2[d] + 1e-5f);
    float sh2 = be2[d] - m2[d] * sc2;

    // hb = bn2(u2 @ w2b + b2b)   (no relu between conv2 and bn2)
#pragma unroll
    for (int r = 0; r < 4; ++r) {
        int n = r * 8 + ng;
        float acc = b2b[d];
#pragma unroll
        for (int k = 0; k < DIM_; ++k) acc += A[n * 33 + k] * wA[k * DIM_ + d];
        B[n * 33 + d] = acc * sc2 + sh2;
    }
    __syncthreads();

    // f = relu(hb @ fc1w + fc1b) -> overwrite A
#pragma unroll
    for (int r = 0; r < 4; ++r) {
        int n = r * 8 + ng;
        float acc = f1b[d];
#pragma unroll
        for (int k = 0; k < DIM_; ++k) acc += B[n * 33 + k] * wB[k * DIM_ + d];
        A[n * 33 + d] = fmaxf(acc, 0.f);
    }
    __syncthreads();

    // logits + log_softmax (40 cols: thread d owns col d and col 32+(d&7))
    int c2 = 32 + (d & 7);
#pragma unroll
    for (int r = 0; r < 4; ++r) {
        int n = r * 8 + ng;
        float l0 = f2b[d];
        float l1 = f2b[c2];
#pragma unroll
        for (int k = 0; k < DIM_; ++k) {
            float fv = A[n * 33 + k];
            l0 += fv * wC[k * NC_ + d];
            l1 += fv * wC[k * NC_ + c2];
        }
        float mx = fmaxf(l0, l1);
#pragma unroll
        for (int off = 16; off; off >>= 1) mx = fmaxf(mx, __shfl_xor(mx, off));
        float se = __expf(l0 - mx) + ((d < 8) ? __expf(l1 - mx) : 0.f);
#pragma unroll
        for (int off = 16; off; off >>= 1) se += __shfl_xor(se, off);
        float lse = mx + __logf(se);
        size_t ob = (size_t)(blockIdx.x * 32 + n) * NC_;
        out[ob + d] = l0 - lse;
        if (d < 8) out[ob + 32 + d] = l1 - lse;
    }
}

// ---------------------------------------------------------------------------
extern "C" void kernel_launch(void* const* d_in, const int* in_sizes, int n_in,
                              void* d_out, int out_size, void* d_ws, size_t ws_size,
                              hipStream_t stream) {
    const float* x   = (const float*)d_in[0];
    const void*  edg = d_in[1];
    const float* w1a = (const float*)d_in[2];
    const float* b1a = (const float*)d_in[3];
    const float* w1b = (const float*)d_in[4];
    const float* b1b = (const float*)d_in[5];
    const float* w2a = (const float*)d_in[6];
    const float* b2a = (const float*)d_in[7];
    const float* w2b = (const float*)d_in[8];
    const float* b2b = (const float*)d_in[9];
    const float* g1  = (const float*)d_in[10];
    const float* be1 = (const float*)d_in[11];
    const float* m1  = (const float*)d_in[12];
    const float* v1  = (const float*)d_in[13];
    const float* g2  = (const float*)d_in[14];
    const float* be2 = (const float*)d_in[15];
    const float* m2  = (const float*)d_in[16];
    const float* v2  = (const float*)d_in[17];
    const float* f1w = (const float*)d_in[18];
    const float* f1b = (const float*)d_in[19];
    const float* f2w = (const float*)d_in[20];
    const float* f2b = (const float*)d_in[21];
    float* out = (float*)d_out;

    // Workspace layout (byte offsets, 128B-aligned)
    char* ws = (char*)d_ws;
    int* flag   = (int*)ws;                      // 256 B
    int* bcnt   = (int*)(ws + 256);              // 782 ints (pad 3328)
    int* bbase  = (int*)(ws + 3584);             // 782 ints (pad 3328)
    int* ghist  = (int*)(ws + 6912);             // 512*782 ints = 1601536 B
    int* gcurT  = (int*)(ws + 1608448);          // 782*512 ints = 1601536 B
    int* offs   = (int*)(ws + 3209984);          // N+1 ints (pad 400128)
    int* packed = (int*)(ws + 3610112);          // E ints
    int* csr    = (int*)(ws + 10010112);         // E ints
    __hip_bfloat16* yh = (__hip_bfloat16*)(ws + 16410112);  // N*DIM bf16
    __hip_bfloat16* zh = (__hip_bfloat16*)(ws + 22810112);  // N*DIM bf16

    detect_kernel<<<1, 64, 0, stream>>>(edg, flag);

    // ---- Build per-node CSR, fully deterministic, no global atomics ----
    chist_kernel<<<NCHUNK, 256, 0, stream>>>(edg, flag, ghist);
    colscan_kernel<<<NB_BKT, NCHUNK, 0, stream>>>(ghist, gcurT, bcnt);
    bscan_kernel<<<1, 1024, 0, stream>>>(bcnt, bbase, offs);
    dscatter_kernel<<<NCHUNK, 256, 0, stream>>>(edg, flag, bbase, gcurT, packed);
    bsort_kernel<<<NB_BKT, 256, 0, stream>>>(bcnt, bbase, packed, offs, csr);

    // ---- Layer 1: project 128->32 BEFORE aggregation (linearity) ----
    proj1_kernel<<<N_ / 32, 256, 0, stream>>>(x, w1a, yh);
    aggmlp1_kernel<<<N_ / 32, 256, 0, stream>>>(offs, csr, yh, b1a, w1b, b1b,
                                                g1, be1, m1, v1, w2a, zh);

    // ---- Layer 2 + head (w2a folded pre-aggregation) ----
    aggmlp2_kernel<<<N_ / 32, 256, 0, stream>>>(offs, csr, zh, b2a, w2b, b2b,
                                                g2, be2, m2, v2, f1w, f1b, f2w, f2b, out);
}

// Round 6
// 329.748 us; speedup vs baseline: 2.9204x; 1.0830x over previous
//
#include <hip/hip_runtime.h>
#include <hip/hip_bf16.h>

// Problem constants
static constexpr int N_   = 100000;
static constexpr int E_   = 1600000;
static constexpr int FIN_ = 128;
static constexpr int DIM_ = 32;
static constexpr int NC_  = 40;
static constexpr int NB_BKT = (N_ + 127) / 128;   // 782 buckets of 128 dst nodes
static constexpr int NCHUNK = 256;                // edge chunks
static constexpr int EPC    = E_ / NCHUNK;        // 6250 edges per chunk (exact)

// ---------------------------------------------------------------------------
// Edge dtype detection: reference says int64, but JAX x64-off gives int32.
// ---------------------------------------------------------------------------
__global__ void detect_kernel(const void* __restrict__ edge, int* __restrict__ flag) {
    if (blockIdx.x == 0) {
        const long long* p = (const long long*)edge;
        long long v = p[threadIdx.x & 63];
        bool bad = (v < 0 || v >= (long long)N_);
        unsigned long long m = __ballot(bad);
        if (threadIdx.x == 0) *flag = (m == 0ull) ? 1 : 0;   // 1 => int64 layout
    }
}

__device__ __forceinline__ int edge_at(const void* e, int is64, long long i) {
    return is64 ? (int)((const long long*)e)[i] : ((const int*)e)[i];
}

__device__ __forceinline__ float bflo(unsigned u) { return __uint_as_float(u << 16); }
__device__ __forceinline__ float bfhi(unsigned u) { return __uint_as_float(u & 0xffff0000u); }

// ---------------------------------------------------------------------------
// Build 1: per-chunk bucket histogram in LDS -> ghist[b][k]  (no global atomics)
// ---------------------------------------------------------------------------
__global__ __launch_bounds__(256) void chist_kernel(const void* __restrict__ edge,
                                                    const int* __restrict__ flag,
                                                    int* __restrict__ ghist) {
    __shared__ int lh[NB_BKT];
    for (int i = threadIdx.x; i < NB_BKT; i += 256) lh[i] = 0;
    __syncthreads();
    int f = *flag;
    int b = blockIdx.x;
    int end = b * EPC + EPC;
    for (int e = b * EPC + threadIdx.x; e < end; e += 256) {
        int d = edge_at(edge, f, (long long)E_ + e);
        atomicAdd(&lh[d >> 7], 1);           // LDS int atomic
    }
    __syncthreads();
    for (int i = threadIdx.x; i < NB_BKT; i += 256) ghist[b * NB_BKT + i] = lh[i];
}

// ---------------------------------------------------------------------------
// Build 2: per-bucket column scan of ghist -> gcurT[k][b] (excl) + bcnt[k]
// ---------------------------------------------------------------------------
__global__ __launch_bounds__(NCHUNK) void colscan_kernel(const int* __restrict__ ghist,
                                                         int* __restrict__ gcurT,
                                                         int* __restrict__ bcnt) {
    __shared__ int a[NCHUNK];
    int k = blockIdx.x, tid = threadIdx.x;
    int v = ghist[tid * NB_BKT + k];
    a[tid] = v;
    __syncthreads();
    for (int off = 1; off < NCHUNK; off <<= 1) {
        int t = a[tid] + ((tid >= off) ? a[tid - off] : 0);
        __syncthreads();
        a[tid] = t;
        __syncthreads();
    }
    gcurT[k * NCHUNK + tid] = a[tid] - v;     // exclusive within column
    if (tid == NCHUNK - 1) bcnt[k] = a[tid];  // column total
}

// ---------------------------------------------------------------------------
// Build 3: single-block exclusive scan of bucket totals -> bbase, offs[N]=E
// ---------------------------------------------------------------------------
__global__ __launch_bounds__(1024) void bscan_kernel(const int* __restrict__ bcnt,
                                                     int* __restrict__ bbase,
                                                     int* __restrict__ offs) {
    __shared__ int a[1024];
    int tid = threadIdx.x;
    int v = (tid < NB_BKT) ? bcnt[tid] : 0;
    a[tid] = v;
    __syncthreads();
    for (int off = 1; off < 1024; off <<= 1) {
        int t = a[tid] + ((tid >= off) ? a[tid - off] : 0);
        __syncthreads();
        a[tid] = t;
        __syncthreads();
    }
    if (tid < NB_BKT) bbase[tid] = a[tid] - v;
    if (tid == NB_BKT - 1) offs[N_] = a[tid];   // == E_
}

// ---------------------------------------------------------------------------
// Build 4: deterministic scatter into bucket regions; cursors in LDS.
// ---------------------------------------------------------------------------
__global__ __launch_bounds__(256) void dscatter_kernel(const void* __restrict__ edge,
                                                       const int* __restrict__ flag,
                                                       const int* __restrict__ bbase,
                                                       const int* __restrict__ gcurT,
                                                       int* __restrict__ packed) {
    __shared__ int cur[NB_BKT];
    int b = blockIdx.x, tid = threadIdx.x;
    for (int k = tid; k < NB_BKT; k += 256) cur[k] = bbase[k] + gcurT[k * NCHUNK + b];
    __syncthreads();
    int f = *flag;
    int end = b * EPC + EPC;
    for (int e = b * EPC + tid; e < end; e += 256) {
        int s = edge_at(edge, f, e);
        int d = edge_at(edge, f, (long long)E_ + e);
        int pos = atomicAdd(&cur[d >> 7], 1);     // LDS int atomic
        packed[pos] = s | ((d & 127) << 17);      // N < 2^17
    }
}

// ---------------------------------------------------------------------------
// Build 5: per-bucket counting sort in LDS -> exact offs[] + csr[] (src ids).
// ---------------------------------------------------------------------------
__global__ __launch_bounds__(256) void bsort_kernel(const int* __restrict__ bcnt,
                                                    const int* __restrict__ bbase,
                                                    const int* __restrict__ packed,
                                                    int* __restrict__ offs,
                                                    int* __restrict__ csr) {
    __shared__ int c[128];
    __shared__ int cur[128];
    int tid = threadIdx.x;
    int b = blockIdx.x;
    int beg = bbase[b], cnt = bcnt[b];
    if (tid < 128) c[tid] = 0;
    __syncthreads();
    for (int i = tid; i < cnt; i += 256)
        atomicAdd(&c[packed[beg + i] >> 17], 1);
    __syncthreads();
    int myv = (tid < 128) ? c[tid] : 0;
    for (int off = 1; off < 128; off <<= 1) {
        int t = 0;
        if (tid < 128) t = c[tid] + ((tid >= off) ? c[tid - off] : 0);
        __syncthreads();
        if (tid < 128) c[tid] = t;
        __syncthreads();
    }
    if (tid < 128) {
        int ex = c[tid] - myv;
        cur[tid] = ex;
        int node = b * 128 + tid;
        if (node < N_) offs[node] = beg + ex;
    }
    __syncthreads();
    for (int i = tid; i < cnt; i += 256) {
        int v = packed[beg + i];
        int p = atomicAdd(&cur[v >> 17], 1);
        csr[beg + p] = v & 0x1FFFF;
    }
}

// ---------------------------------------------------------------------------
// yh = bf16(x @ w1a)   (100000x128 @ 128x32). 32 nodes per block.
// ---------------------------------------------------------------------------
__global__ __launch_bounds__(256) void proj1_kernel(const float* __restrict__ x,
                                                    const float* __restrict__ w,
                                                    __hip_bfloat16* __restrict__ yh) {
    __shared__ float wsm[FIN_ * DIM_];
    __shared__ float xs[32][FIN_];
    int tid = threadIdx.x;

    const float4* w4 = (const float4*)w;
    float4* ws4 = (float4*)wsm;
    for (int i = tid; i < FIN_ * DIM_ / 4; i += 256) ws4[i] = w4[i];

    int nodeBase = blockIdx.x * 32;
    const float4* x4 = (const float4*)(x + (size_t)nodeBase * FIN_);
    float4* xs4 = (float4*)&xs[0][0];
    for (int i = tid; i < 32 * FIN_ / 4; i += 256) xs4[i] = x4[i];
    __syncthreads();

    int d = tid & 31, ns = tid >> 5;
    for (int rep = 0; rep < 4; ++rep) {
        int node = ns + rep * 8;
        float acc = 0.f;
#pragma unroll 4
        for (int k = 0; k < FIN_; ++k) acc += xs[node][k] * wsm[k * DIM_ + d];
        yh[(size_t)(nodeBase + node) * DIM_ + d] = __float2bfloat16(acc);
    }
}

// ---------------------------------------------------------------------------
// Gather helper: 4-wide unrolled CSR gather, 8 lanes x 8B per node row.
// ---------------------------------------------------------------------------
__device__ __forceinline__ void gather_row(const int* __restrict__ csr,
                                           const char* __restrict__ vb,
                                           int beg, int end, int loff,
                                           float& a0, float& a1, float& a2, float& a3) {
    int i = beg;
    for (; i + 3 < end; i += 4) {
        int s0 = csr[i], s1 = csr[i + 1], s2 = csr[i + 2], s3 = csr[i + 3];
        uint2 u0 = *(const uint2*)(vb + (((size_t)s0) << 6) + loff);
        uint2 u1 = *(const uint2*)(vb + (((size_t)s1) << 6) + loff);
        uint2 u2 = *(const uint2*)(vb + (((size_t)s2) << 6) + loff);
        uint2 u3 = *(const uint2*)(vb + (((size_t)s3) << 6) + loff);
        a0 += (bflo(u0.x) + bflo(u1.x)) + (bflo(u2.x) + bflo(u3.x));
        a1 += (bfhi(u0.x) + bfhi(u1.x)) + (bfhi(u2.x) + bfhi(u3.x));
        a2 += (bflo(u0.y) + bflo(u1.y)) + (bflo(u2.y) + bflo(u3.y));
        a3 += (bfhi(u0.y) + bfhi(u1.y)) + (bfhi(u2.y) + bfhi(u3.y));
    }
    for (; i < end; ++i) {
        int s0 = csr[i];
        uint2 u0 = *(const uint2*)(vb + (((size_t)s0) << 6) + loff);
        a0 += bflo(u0.x); a1 += bfhi(u0.x); a2 += bflo(u0.y); a3 += bfhi(u0.y);
    }
}

// ---------------------------------------------------------------------------
// Fused 1: gather over bf16 y, then u=relu(agg+y+b1a);
// hb=bn1(relu(u@w1b+b1b)); zh=bf16(hb@w2a).
// ---------------------------------------------------------------------------
__global__ __launch_bounds__(256) void aggmlp1_kernel(const int* __restrict__ offs,
                                                      const int* __restrict__ csr,
                                                      const __hip_bfloat16* __restrict__ yh,
                                                      const float* __restrict__ b1a,
                                                      const float* __restrict__ w1b,
                                                      const float* __restrict__ b1b,
                                                      const float* __restrict__ g1,
                                                      const float* __restrict__ be1,
                                                      const float* __restrict__ m1,
                                                      const float* __restrict__ v1,
                                                      const float* __restrict__ w2a,
                                                      __hip_bfloat16* __restrict__ zh) {
    __shared__ float A[32 * 33];
    __shared__ float B[32 * 33];
    __shared__ float w1s[DIM_ * DIM_];
    __shared__ float w2s[DIM_ * DIM_];
    int tid = threadIdx.x;
    for (int i = tid; i < DIM_ * DIM_; i += 256) { w1s[i] = w1b[i]; w2s[i] = w2a[i]; }

    // --- gather-aggregate phase ---
    int nl = tid >> 3, lane = tid & 7;       // 8 lanes x 8B = one 64B row
    int node = blockIdx.x * 32 + nl;
    int beg = offs[node], end = offs[node + 1];
    float a0 = 0.f, a1 = 0.f, a2 = 0.f, a3 = 0.f;
    gather_row(csr, (const char*)yh, beg, end, lane << 3, a0, a1, a2, a3);
    {
        float* p = &A[nl * 33 + lane * 4];
        p[0] = a0; p[1] = a1; p[2] = a2; p[3] = a3;
    }
    __syncthreads();

    int d = tid & 31, ng = tid >> 5;
    size_t gbase = (size_t)blockIdx.x * 32 * DIM_;

    // u = relu(agg + y + b1a)  (elementwise, in place over A)
#pragma unroll
    for (int r = 0; r < 4; ++r) {
        int n = r * 8 + ng;
        float yv = __bfloat162float(yh[gbase + n * DIM_ + d]);
        A[n * 33 + d] = fmaxf(A[n * 33 + d] + yv + b1a[d], 0.f);
    }
    __syncthreads();

    float sc1 = g1[d] * rsqrtf(v1[d] + 1e-5f);
    float sh1 = be1[d] - m1[d] * sc1;

    // hb = bn1(relu(u @ w1b + b1b))
#pragma unroll
    for (int r = 0; r < 4; ++r) {
        int n = r * 8 + ng;
        float acc = b1b[d];
#pragma unroll
        for (int k = 0; k < DIM_; ++k) acc += A[n * 33 + k] * w1s[k * DIM_ + d];
        B[n * 33 + d] = fmaxf(acc, 0.f) * sc1 + sh1;
    }
    __syncthreads();

    // z = hb @ w2a  -> bf16
#pragma unroll
    for (int r = 0; r < 4; ++r) {
        int n = r * 8 + ng;
        float acc = 0.f;
#pragma unroll
        for (int k = 0; k < DIM_; ++k) acc += B[n * 33 + k] * w2s[k * DIM_ + d];
        zh[gbase + n * DIM_ + d] = __float2bfloat16(acc);
    }
}

// ---------------------------------------------------------------------------
// Fused 2: gather over bf16 z, then u=relu(agg+z+b2a); hb=bn2(u@w2b+b2b);
// f=relu(hb@fc1w+fc1b); logits=f@fc2w+fc2b; out=log_softmax(logits).
// wC (f2w) is loaded into B's LDS space after B is dead -> 17.5 KB total.
// ---------------------------------------------------------------------------
__global__ __launch_bounds__(256) void aggmlp2_kernel(const int* __restrict__ offs,
                                                      const int* __restrict__ csr,
                                                      const __hip_bfloat16* __restrict__ zh,
                                                      const float* __restrict__ b2a,
                                                      const float* __restrict__ w2b,
                                                      const float* __restrict__ b2b,
                                                      const float* __restrict__ g2,
                                                      const float* __restrict__ be2,
                                                      const float* __restrict__ m2,
                                                      const float* __restrict__ v2,
                                                      const float* __restrict__ f1w,
                                                      const float* __restrict__ f1b,
                                                      const float* __restrict__ f2w,
                                                      const float* __restrict__ f2b,
                                                      float* __restrict__ out) {
    __shared__ float A[32 * 33];
    __shared__ float BC[DIM_ * NC_];   // phases 3-4: B (hb, 32*33=1056); phase 5: wC (1280)
    __shared__ float wA[DIM_ * DIM_];
    __shared__ float wB[DIM_ * DIM_];
    int tid = threadIdx.x;
    for (int i = tid; i < DIM_ * DIM_; i += 256) { wA[i] = w2b[i]; wB[i] = f1w[i]; }

    // --- gather-aggregate phase ---
    int nl = tid >> 3, lane = tid & 7;
    int node = blockIdx.x * 32 + nl;
    int beg = offs[node], end = offs[node + 1];
    float a0 = 0.f, a1 = 0.f, a2 = 0.f, a3 = 0.f;
    gather_row(csr, (const char*)zh, beg, end, lane << 3, a0, a1, a2, a3);
    {
        float* p = &A[nl * 33 + lane * 4];
        p[0] = a0; p[1] = a1; p[2] = a2; p[3] = a3;
    }
    __syncthreads();

    int d = tid & 31, ng = tid >> 5;
    size_t gbase = (size_t)blockIdx.x * 32 * DIM_;

    // u2 = relu(agg + z + b2a)
#pragma unroll
    for (int r = 0; r < 4; ++r) {
        int n = r * 8 + ng;
        float zv = __bfloat162float(zh[gbase + n * DIM_ + d]);
        A[n * 33 + d] = fmaxf(A[n * 33 + d] + zv + b2a[d], 0.f);
    }
    __syncthreads();

    float sc2 = g2[d] * rsqrtf(v2[d] + 1e-5f);
    float sh2 = be2[d] - m2[d] * sc2;

    // hb = bn2(u2 @ w2b + b2b)   (no relu between conv2 and bn2) -> BC
#pragma unroll
    for (int r = 0; r < 4; ++r) {
        int n = r * 8 + ng;
        float acc = b2b[d];
#pragma unroll
        for (int k = 0; k < DIM_; ++k) acc += A[n * 33 + k] * wA[k * DIM_ + d];
        BC[n * 33 + d] = acc * sc2 + sh2;
    }
    __syncthreads();

    // f = relu(hb @ fc1w + fc1b) -> overwrite A
#pragma unroll
    for (int r = 0; r < 4; ++r) {
        int n = r * 8 + ng;
        float acc = f1b[d];
#pragma unroll
        for (int k = 0; k < DIM_; ++k) acc += BC[n * 33 + k] * wB[k * DIM_ + d];
        A[n * 33 + d] = fmaxf(acc, 0.f);
    }
    __syncthreads();
    // B is dead now -> load wC over it
    for (int i = tid; i < DIM_ * NC_; i += 256) BC[i] = f2w[i];
    __syncthreads();

    // logits + log_softmax (40 cols: thread d owns col d and col 32+(d&7))
    int c2 = 32 + (d & 7);
#pragma unroll
    for (int r = 0; r < 4; ++r) {
        int n = r * 8 + ng;
        float l0 = f2b[d];
        float l1 = f2b[c2];
#pragma unroll
        for (int k = 0; k < DIM_; ++k) {
            float fv = A[n * 33 + k];
            l0 += fv * BC[k * NC_ + d];
            l1 += fv * BC[k * NC_ + c2];
        }
        float mx = fmaxf(l0, l1);
#pragma unroll
        for (int off = 16; off; off >>= 1) mx = fmaxf(mx, __shfl_xor(mx, off));
        float se = __expf(l0 - mx) + ((d < 8) ? __expf(l1 - mx) : 0.f);
#pragma unroll
        for (int off = 16; off; off >>= 1) se += __shfl_xor(se, off);
        float lse = mx + __logf(se);
        size_t ob = (size_t)(blockIdx.x * 32 + n) * NC_;
        out[ob + d] = l0 - lse;
        if (d < 8) out[ob + 32 + d] = l1 - lse;
    }
}

// ---------------------------------------------------------------------------
extern "C" void kernel_launch(void* const* d_in, const int* in_sizes, int n_in,
                              void* d_out, int out_size, void* d_ws, size_t ws_size,
                              hipStream_t stream) {
    const float* x   = (const float*)d_in[0];
    const void*  edg = d_in[1];
    const float* w1a = (const float*)d_in[2];
    const float* b1a = (const float*)d_in[3];
    const float* w1b = (const float*)d_in[4];
    const float* b1b = (const float*)d_in[5];
    const float* w2a = (const float*)d_in[6];
    const float* b2a = (const float*)d_in[7];
    const float* w2b = (const float*)d_in[8];
    const float* b2b = (const float*)d_in[9];
    const float* g1  = (const float*)d_in[10];
    const float* be1 = (const float*)d_in[11];
    const float* m1  = (const float*)d_in[12];
    const float* v1  = (const float*)d_in[13];
    const float* g2  = (const float*)d_in[14];
    const float* be2 = (const float*)d_in[15];
    const float* m2  = (const float*)d_in[16];
    const float* v2  = (const float*)d_in[17];
    const float* f1w = (const float*)d_in[18];
    const float* f1b = (const float*)d_in[19];
    const float* f2w = (const float*)d_in[20];
    const float* f2b = (const float*)d_in[21];
    float* out = (float*)d_out;

    // Workspace layout (byte offsets, 128B-aligned)
    char* ws = (char*)d_ws;
    int* flag   = (int*)ws;                      // 256 B
    int* bcnt   = (int*)(ws + 256);              // 782 ints (pad 3328)
    int* bbase  = (int*)(ws + 3584);             // 782 ints (pad 3328)
    int* ghist  = (int*)(ws + 6912);             // 256*782 ints = 800768 B
    int* gcurT  = (int*)(ws + 807680);           // 782*256 ints = 800768 B
    int* offs   = (int*)(ws + 1608448);          // N+1 ints (pad 400128)
    int* packed = (int*)(ws + 2008576);          // E ints
    int* csr    = (int*)(ws + 8408576);          // E ints
    __hip_bfloat16* yh = (__hip_bfloat16*)(ws + 14808576);  // N*DIM bf16
    __hip_bfloat16* zh = (__hip_bfloat16*)(ws + 21208576);  // N*DIM bf16

    detect_kernel<<<1, 64, 0, stream>>>(edg, flag);

    // ---- Build per-node CSR, fully deterministic, no global atomics ----
    chist_kernel<<<NCHUNK, 256, 0, stream>>>(edg, flag, ghist);
    colscan_kernel<<<NB_BKT, NCHUNK, 0, stream>>>(ghist, gcurT, bcnt);
    bscan_kernel<<<1, 1024, 0, stream>>>(bcnt, bbase, offs);
    dscatter_kernel<<<NCHUNK, 256, 0, stream>>>(edg, flag, bbase, gcurT, packed);
    bsort_kernel<<<NB_BKT, 256, 0, stream>>>(bcnt, bbase, packed, offs, csr);

    // ---- Layer 1: project 128->32 BEFORE aggregation (linearity) ----
    proj1_kernel<<<N_ / 32, 256, 0, stream>>>(x, w1a, yh);
    aggmlp1_kernel<<<N_ / 32, 256, 0, stream>>>(offs, csr, yh, b1a, w1b, b1b,
                                                g1, be1, m1, v1, w2a, zh);

    // ---- Layer 2 + head (w2a folded pre-aggregation) ----
    aggmlp2_kernel<<<N_ / 32, 256, 0, stream>>>(offs, csr, zh, b2a, w2b, b2b,
                                                g2, be2, m2, v2, f1w, f1b, f2w, f2b, out);
}